// Round 8
// baseline (269.530 us; speedup 1.0000x reference)
//
#include <hip/hip_runtime.h>
#include <hip/hip_bf16.h>
#include <math.h>

#define BB 4
#define VV 1024
#define HH 128
#define H2 64
#define EE 523776               // V*(V-1)/2
#define BE (BB * EE)            // 2095104
#define TPB (EE / 16)           // 32736 tiles per batch (even)
#define NTILES (BE / 16)        // 130944
#define NPAIR (NTILES / 2)      // 65472
#define NTHR 256
#define NBLK 1024
#define STRIDE (NBLK * 4)

typedef __attribute__((ext_vector_type(8))) short bf16x8;
typedef __attribute__((ext_vector_type(4))) float f32x4;
typedef __attribute__((ext_vector_type(4))) unsigned u32x4;

// RNE convert — staging only (outside hot loop).
__device__ __forceinline__ short f2bf(float f) {
    __hip_bfloat16 h = __float2bfloat16(f);
    return *reinterpret_cast<short*>(&h);
}

// ONE v_perm_b32: pack two f32 into bf16x2 by truncation.
__device__ __forceinline__ unsigned pkbf(float lo, float hi) {
    return __builtin_amdgcn_perm(__float_as_uint(hi), __float_as_uint(lo),
                                 0x07060302u);
}

__device__ __forceinline__ bf16x8 relu_pack(f32x4 a, f32x4 b) {
    u32x4 r;
    r[0] = pkbf(fmaxf(a[0], 0.f), fmaxf(a[1], 0.f));
    r[1] = pkbf(fmaxf(a[2], 0.f), fmaxf(a[3], 0.f));
    r[2] = pkbf(fmaxf(b[0], 0.f), fmaxf(b[1], 0.f));
    r[3] = pkbf(fmaxf(b[2], 0.f), fmaxf(b[3], 0.f));
    return __builtin_bit_cast(bf16x8, r);
}

// ---------------------------------------------------------------------------
// Round 8 (= R7 resubmitted after infra failure): NO persistent weight
// registers. R4-R6 were stuck at 98us because weights lived in AGPRs
// (VGPR=108 < 128 needed) and every MFMA paid v_accvgpr_read shuttles
// (~700 hidden VALU/pair). Fix: all 24 weight fragments staged once into
// LDS in per-lane order (frag[f][lane], 16B/lane contiguous =>
// conflict-free ds_read_b128), re-read each pair-iteration. Weight access
// is now LGKM traffic, not VALU; regs drop -> 3 waves/SIMD.
// Feature frag unmasked: A1 rows k>=8 are structurally zero, so u!=0 lanes'
// B-slots can hold garbage (product is 0) -- no cndmask.
// ---------------------------------------------------------------------------
__global__ __launch_bounds__(NTHR, 3) void edge_mlp_mfma6(
    const float* __restrict__ vertices,  // [4,1024,3]
    const float* __restrict__ W1,        // [6,128]
    const float* __restrict__ b1,        // [128]
    const float* __restrict__ W2,        // [128,64]
    const float* __restrict__ b2,        // [64]
    const float* __restrict__ W3,        // [64]
    const float* __restrict__ b3,        // [1]
    float* __restrict__ out)             // [BE probs][2*EE indices-as-float]
{
    // frag table: ids 0..7 = A1[p][q] (f = p*2+q), 8..23 = A2[mt][p] (f = 8+mt*4+p)
    __shared__ __align__(16) bf16x8 wfrag[24 * 64];      // 24 KB

    const int lane = threadIdx.x & 63;
    const int col  = lane & 15;          // edge slot (N dim everywhere)
    const int u    = lane >> 4;
    const int wid  = threadIdx.x >> 6;

    const f32x4 zero4 = {0.f, 0.f, 0.f, 0.f};

    // ---- stage weight fragments into LDS (each wave does 6 frags) ----
    for (int f = wid; f < 24; f += 4) {
        bf16x8 frag;
        if (f < 8) {
            // L1: A-row permuted so L1's C/D layout IS L2's B-frag layout:
            // h = 32p + 8*(col>>2) + 4q + (col&3); element k = 8u+r
            const int p = f >> 1, q = f & 1;
            const int h = 32 * p + 8 * (col >> 2) + 4 * q + (col & 3);
#pragma unroll
            for (int r = 0; r < 8; ++r) {
                const int k = 8 * u + r;
                float w = 0.0f;
                if (k < 6)       w = W1[k * HH + h];
                else if (k == 6) w = b1[h];
                frag[r] = f2bf(w);
            }
        } else {
            // L2: A2[mt][p][r] = W2[h=32p+8u+r][n2=16mt+col]
            const int mt = (f - 8) >> 2, p = (f - 8) & 3;
            const int n2 = 16 * mt + col;
#pragma unroll
            for (int r = 0; r < 8; ++r) {
                const int h = 32 * p + 8 * u + r;
                frag[r] = f2bf(W2[h * H2 + n2]);
            }
        }
        wfrag[f * 64 + lane] = frag;
    }

    // ---- small epilogue constants in registers ----
    f32x4 cinit[4];
    float w3c[16];
#pragma unroll
    for (int mt = 0; mt < 4; ++mt)
#pragma unroll
        for (int q = 0; q < 4; ++q) {
            const int n2 = 16 * mt + 4 * u + q;
            cinit[mt][q]    = b2[n2];
            w3c[mt * 4 + q] = W3[n2];
        }
    const float b3v = b3[0];

    __syncthreads();

    const int gw = blockIdx.x * 4 + wid;

    for (int pt = gw; pt < NPAIR; pt += STRIDE) {
        const int tt0 = pt * 2;               // tiles tt0, tt0+1 share batch b
        const int b   = tt0 / TPB;
        const int e00 = (tt0 - b * TPB) * 16;

        // ---- decode + vertex load + feature pack (all lanes, no mask) ----
        bf16x8 bfv[2];
        int iv[2], jv[2];
#pragma unroll
        for (int s = 0; s < 2; ++s) {
            const int e  = e00 + s * 16 + col;
            const int rr = EE - 1 - e;
            const float sq = sqrtf((float)(8 * rr + 1));   // exact: < 2^23
            int m = (int)(0.5f * (sq - 1.0f));
            if ((m + 1) * (m + 2) / 2 <= rr) ++m;
            if (m * (m + 1) / 2 > rr) --m;
            const int pp = rr - m * (m + 1) / 2;
            iv[s] = VV - 2 - m;
            jv[s] = VV - 1 - pp;
            const float* pvi = vertices + (b * VV + iv[s]) * 3;
            const float* pvj = vertices + (b * VV + jv[s]) * 3;
            u32x4 fb;
            fb[0] = pkbf(pvi[0], pvi[1]);
            fb[1] = pkbf(pvi[2], pvj[0]);
            fb[2] = pkbf(pvj[1], pvj[2]);
            fb[3] = 0x00003F80u;              // bf16(1.0) in k=6 (bias), 0 in k=7
            bfv[s] = __builtin_bit_cast(bf16x8, fb);
        }

        f32x4 d2[2][4];

        // ---- p = 0 (b2 rides in as C-in) ----
        {
            const bf16x8 a10 = wfrag[0 * 64 + lane];   // A1[0][0]
            const bf16x8 a11 = wfrag[1 * 64 + lane];   // A1[0][1]
            const bf16x8 w20 = wfrag[(8 + 0) * 64 + lane];   // A2[0][0]
            const bf16x8 w21 = wfrag[(8 + 4) * 64 + lane];   // A2[1][0]
            const bf16x8 w22 = wfrag[(8 + 8) * 64 + lane];   // A2[2][0]
            const bf16x8 w23 = wfrag[(8 + 12) * 64 + lane];  // A2[3][0]
#pragma unroll
            for (int s = 0; s < 2; ++s) {
                f32x4 dA = __builtin_amdgcn_mfma_f32_16x16x32_bf16(a10, bfv[s], zero4, 0, 0, 0);
                f32x4 dB = __builtin_amdgcn_mfma_f32_16x16x32_bf16(a11, bfv[s], zero4, 0, 0, 0);
                bf16x8 Bh = relu_pack(dA, dB);
                d2[s][0] = __builtin_amdgcn_mfma_f32_16x16x32_bf16(w20, Bh, cinit[0], 0, 0, 0);
                d2[s][1] = __builtin_amdgcn_mfma_f32_16x16x32_bf16(w21, Bh, cinit[1], 0, 0, 0);
                d2[s][2] = __builtin_amdgcn_mfma_f32_16x16x32_bf16(w22, Bh, cinit[2], 0, 0, 0);
                d2[s][3] = __builtin_amdgcn_mfma_f32_16x16x32_bf16(w23, Bh, cinit[3], 0, 0, 0);
            }
        }

        // ---- p = 1..3 ----
#pragma unroll
        for (int p = 1; p < 4; ++p) {
            const bf16x8 a10 = wfrag[(p * 2 + 0) * 64 + lane];
            const bf16x8 a11 = wfrag[(p * 2 + 1) * 64 + lane];
            const bf16x8 w20 = wfrag[(8 + 0 * 4 + p) * 64 + lane];
            const bf16x8 w21 = wfrag[(8 + 1 * 4 + p) * 64 + lane];
            const bf16x8 w22 = wfrag[(8 + 2 * 4 + p) * 64 + lane];
            const bf16x8 w23 = wfrag[(8 + 3 * 4 + p) * 64 + lane];
#pragma unroll
            for (int s = 0; s < 2; ++s) {
                f32x4 dA = __builtin_amdgcn_mfma_f32_16x16x32_bf16(a10, bfv[s], zero4, 0, 0, 0);
                f32x4 dB = __builtin_amdgcn_mfma_f32_16x16x32_bf16(a11, bfv[s], zero4, 0, 0, 0);
                bf16x8 Bh = relu_pack(dA, dB);
                d2[s][0] = __builtin_amdgcn_mfma_f32_16x16x32_bf16(w20, Bh, d2[s][0], 0, 0, 0);
                d2[s][1] = __builtin_amdgcn_mfma_f32_16x16x32_bf16(w21, Bh, d2[s][1], 0, 0, 0);
                d2[s][2] = __builtin_amdgcn_mfma_f32_16x16x32_bf16(w22, Bh, d2[s][2], 0, 0, 0);
                d2[s][3] = __builtin_amdgcn_mfma_f32_16x16x32_bf16(w23, Bh, d2[s][3], 0, 0, 0);
            }
        }

        // ---- layer 3 + sigmoid + store ----
#pragma unroll
        for (int s = 0; s < 2; ++s) {
            float a0 = 0.f, a1 = 0.f, a2 = 0.f, a3 = 0.f;
#pragma unroll
            for (int q = 0; q < 4; ++q) {
                a0 = fmaf(fmaxf(d2[s][0][q], 0.f), w3c[q],      a0);
                a1 = fmaf(fmaxf(d2[s][1][q], 0.f), w3c[4 + q],  a1);
                a2 = fmaf(fmaxf(d2[s][2][q], 0.f), w3c[8 + q],  a2);
                a3 = fmaf(fmaxf(d2[s][3][q], 0.f), w3c[12 + q], a3);
            }
            float acc = (a0 + a1) + (a2 + a3);
            acc += __shfl_xor(acc, 16);
            acc += __shfl_xor(acc, 32);

            if (u == 0) {
                const float x = acc + b3v;
                const float prob = __builtin_amdgcn_rcpf(1.0f + __expf(-x));
                out[(tt0 + s) * 16 + col] = prob;
                if (b == 0) {
                    const int e = e00 + s * 16 + col;
                    *(float2*)(&out[BE + 2 * e]) =
                        make_float2((float)iv[s], (float)jv[s]);
                }
            }
        }
    }
}

extern "C" void kernel_launch(void* const* d_in, const int* in_sizes, int n_in,
                              void* d_out, int out_size, void* d_ws, size_t ws_size,
                              hipStream_t stream) {
    const float* vertices = (const float*)d_in[0];
    const float* W1 = (const float*)d_in[1];
    const float* b1 = (const float*)d_in[2];
    const float* W2 = (const float*)d_in[3];
    const float* b2 = (const float*)d_in[4];
    const float* W3 = (const float*)d_in[5];
    const float* b3 = (const float*)d_in[6];
    float* out = (float*)d_out;

    edge_mlp_mfma6<<<NBLK, NTHR, 0, stream>>>(vertices, W1, b1, W2, b2, W3, b3, out);
}